// Round 8
// baseline (169.645 us; speedup 1.0000x reference)
//
#include <hip/hip_runtime.h>
#include <math.h>

#pragma clang fp contract(off)

#define VV 5
#define BB 2
#define CC 32
#define HH 128
#define WW 128
#define DD 32
#define GG 8
#define HWW (HH*WW)
#define TRBLOCKS (VV*BB*(HWW/64))   // 2560 transpose blocks

typedef float v2f __attribute__((ext_vector_type(2)));

// ---------------------------------------------------------------------------
// Kernel 1 (fused): transpose features [VB,C,H,W] -> [VB,H,W,C]  +  proj setup.
// (unchanged — bit-exact copy; proj math bit-frozen at r9)
// ---------------------------------------------------------------------------
__global__ __launch_bounds__(256) void prep_kernel(const float* __restrict__ fea,
                                                   float* __restrict__ featT,
                                                   const float* __restrict__ pm,
                                                   float* __restrict__ wproj) {
#pragma clang fp contract(off)
    int t = threadIdx.x;
    if (blockIdx.x == TRBLOCKS) {
        int tid = t;
        if (tid >= BB * (VV - 1)) return;
        int b = tid / (VV - 1);
        int v = tid % (VV - 1) + 1;

        float refP[4][4], srcP[4][4];
        for (int which = 0; which < 2; which++) {
            int view = (which == 0) ? 0 : v;
            const float* base = pm + (size_t)(b * VV + view) * 2 * 16;
            const float* ext  = base;
            const float* intr = base + 16;
            float (*M)[4] = (which == 0) ? refP : srcP;
            for (int r = 0; r < 3; r++)
                for (int c = 0; c < 4; c++) {
                    float s = 0.f;
                    for (int k = 0; k < 3; k++)
                        s = fmaf(intr[r * 4 + k], ext[k * 4 + c], s);  // einsum FMA chain
                    M[r][c] = s;
                }
            for (int c = 0; c < 4; c++) M[3][c] = ext[12 + c];
        }

        float A[4][4];
        for (int r = 0; r < 4; r++)
            for (int c = 0; c < 4; c++) A[r][c] = refP[r][c];
        int ipiv[4];
        for (int j = 0; j < 4; j++) {
            int p = j; float amax = fabsf(A[j][j]);
            for (int i = j + 1; i < 4; i++) {
                float tt = fabsf(A[i][j]);
                if (tt > amax) { amax = tt; p = i; }
            }
            ipiv[j] = p;
            if (p != j)
                for (int c = 0; c < 4; c++) { float tt = A[j][c]; A[j][c] = A[p][c]; A[p][c] = tt; }
            float rcp = 1.0f / A[j][j];
            for (int i = j + 1; i < 4; i++) A[i][j] = A[i][j] * rcp;
            for (int i = j + 1; i < 4; i++)
                for (int k = j + 1; k < 4; k++)
                    A[i][k] = fmaf(-A[i][j], A[j][k], A[i][k]);
        }

        float Bm[4][4];
        for (int r = 0; r < 4; r++)
            for (int c = 0; c < 4; c++) Bm[r][c] = (r == c) ? 1.f : 0.f;
        for (int j = 0; j < 4; j++) {
            int p = ipiv[j];
            if (p != j)
                for (int c = 0; c < 4; c++) { float tt = Bm[j][c]; Bm[j][c] = Bm[p][c]; Bm[p][c] = tt; }
        }
        float invd[4];
        for (int k = 0; k < 4; k++) invd[k] = 1.0f / A[k][k];
        for (int c = 0; c < 4; c++) {
            for (int k = 0; k < 4; k++)
                for (int i = k + 1; i < 4; i++)
                    Bm[i][c] = fmaf(-A[i][k], Bm[k][c], Bm[i][c]);
            for (int k = 3; k >= 0; k--) {
                Bm[k][c] = Bm[k][c] * invd[k];
                for (int i = 0; i < k; i++)
                    Bm[i][c] = fmaf(-A[i][k], Bm[k][c], Bm[i][c]);
            }
        }

        float P[3][4];
        for (int r = 0; r < 3; r++)
            for (int c = 0; c < 4; c++) {
                float s = 0.f;
                for (int k = 0; k < 4; k++)
                    s = fmaf(srcP[r][k], Bm[k][c], s);
                P[r][c] = s;
            }
        float* o = wproj + (b * (VV - 1) + (v - 1)) * 12;
        for (int r = 0; r < 3; r++)
            for (int c = 0; c < 3; c++) o[r * 3 + c] = P[r][c];
        for (int r = 0; r < 3; r++) o[9 + r] = P[r][3];
        return;
    }

    __shared__ float tile[64][36];
    int vb = blockIdx.x >> 8;
    int base = (blockIdx.x & 255) * 64;
#pragma unroll
    for (int k = 0; k < 2; k++) {
        int c = (t >> 4) + 16 * k;
        int p = t & 15;
        float4 v = *(const float4*)&fea[((size_t)vb * CC + c) * HWW + base + 4 * p];
        int cs = c ^ ((p & 7) << 2);
        tile[4 * p + 0][cs] = v.x;
        tile[4 * p + 1][cs] = v.y;
        tile[4 * p + 2][cs] = v.z;
        tile[4 * p + 3][cs] = v.w;
    }
    __syncthreads();
#pragma unroll
    for (int m = 0; m < 2; m++) {
        int pl = (t >> 3) + 32 * m;
        int q = t & 7;
        int sw = ((pl >> 2) & 7) << 2;
        float4 v = *(const float4*)&tile[pl][(4 * q) ^ sw];
        *(float4*)&featT[((size_t)vb * HWW + base + pl) * CC + 4 * q] = v;
    }
}

// ---------------------------------------------------------------------------
// Kernel 2: R3/R7 structure + 2-VIEW ILP INTERLEAVE.
// Ledger: occupancy 28->78% (R4/R6), granularity (R6), L2 locality (R7 swizzle:
// FETCH 18.8->11.9 MB) all verified by counters and all left duration at
// 87-94 us, VALUBusy 53-55%. Remaining lever: per-wave ILP — in-order issue
// means view v+1's gathers can't issue until view v's serial chain (project ->
// gather -> correlate -> butterfly -> exp -> LDS round-trip -> 31 serial adds
// -> IEEE div) retires. Process views in PAIRS: one merged g-loop issues both
// views' loads (overlapped memory phases), and the two independent softmax
// chains interleave in the scheduler -> per-wave dependent latency ~halves.
// Bit-exact: per-view op chains byte-identical; accumulation strictly
// v-ordered (A then B); per-chain sum order unchanged; s_e double-buffered;
// s_ref value shared (identical value, identical multiply).
// ---------------------------------------------------------------------------
__global__ __launch_bounds__(256) void main_kernel(const float* __restrict__ featT,
                                                   const float* __restrict__ wproj,
                                                   const float* __restrict__ depth_hypo,
                                                   const float* __restrict__ reg_w,
                                                   float* __restrict__ out) {
#pragma clang fp contract(off)
    __shared__ float s_ref[8][32];
    __shared__ float s_e[2][8][32];
    __shared__ float s_proj[4][12];
    __shared__ float s_regw[8];

    int t = threadIdx.x;
    int d = t & 31, pl = t >> 5;
    int base = t & 32;

    // XCD-aware bijective swizzle (R7: halves FETCH, keep)
    int bid = blockIdx.x;                       // nwg = 4096
    int swz = (bid & 7) * (4096 >> 3) + (bid >> 3);

    int pixbase = swz * 8;
    int b = pixbase / HWW;
    int hwb = pixbase - b * HWW;

    s_ref[pl][d] = featT[((size_t)(b * HWW + hwb + pl)) * CC + d];
    if (t < 48) s_proj[t / 12][t % 12] = wproj[b * (VV - 1) * 12 + t];
    if (t < 8) s_regw[t] = reg_w[t];
    __syncthreads();

    int hw = hwb + pl;
    int y = hw >> 7, x = hw & (WW - 1);
    float fx = (float)x, fy = (float)y;
    float dep = depth_hypo[(size_t)(b * DD + d) * HWW + hw];

    float accs[8];
#pragma unroll
    for (int g = 0; g < 8; g++) accs[g] = 0.f;
    float cws = 1e-8f;

    for (int vp = 0; vp < 2; vp++) {
        // ---------------- view A = 2*vp+? addresses & weights ----------------
        const float* prA = s_proj[2 * vp];
        const float* prB = s_proj[2 * vp + 1];

        // --- view A coords (chain identical to serial version) ---
        float rxA = fmaf(prA[1], fy, prA[0] * fx) + prA[2];
        float ryA = fmaf(prA[4], fy, prA[3] * fx) + prA[5];
        float rzA = fmaf(prA[7], fy, prA[6] * fx) + prA[8];
        float XA = rxA * dep + prA[9];
        float YA = ryA * dep + prA[10];
        float ZA = rzA * dep + prA[11];
        if (ZA == 0.f) ZA = 1e-9f;
        float pxA = XA / ZA, pyA = YA / ZA;
        float x0fA = floorf(pxA), y0fA = floorf(pyA);
        float x1fA = x0fA + 1.0f, y1fA = y0fA + 1.0f;
        float wx1A = pxA - x0fA, wx0A = 1.0f - wx1A;
        float wy1A = pyA - y0fA, wy0A = 1.0f - wy1A;
        bool vx0A = (x0fA >= 0.f) && (x0fA <= (float)(WW - 1));
        bool vx1A = (x1fA >= 0.f) && (x1fA <= (float)(WW - 1));
        bool vy0A = (y0fA >= 0.f) && (y0fA <= (float)(HH - 1));
        bool vy1A = (y1fA >= 0.f) && (y1fA <= (float)(HH - 1));
        int xc0A = (int)fminf(fmaxf(x0fA, 0.f), (float)(WW - 1));
        int xc1A = (int)fminf(fmaxf(x1fA, 0.f), (float)(WW - 1));
        int yc0A = (int)fminf(fmaxf(y0fA, 0.f), (float)(HH - 1));
        int yc1A = (int)fminf(fmaxf(y1fA, 0.f), (float)(HH - 1));
        float w00A = (wx0A * wy0A) * ((vx0A && vy0A) ? 1.f : 0.f);
        float w10A = (wx1A * wy0A) * ((vx1A && vy0A) ? 1.f : 0.f);
        float w01A = (wx0A * wy1A) * ((vx0A && vy1A) ? 1.f : 0.f);
        float w11A = (wx1A * wy1A) * ((vx1A && vy1A) ? 1.f : 0.f);
        v2f w00Av = (v2f){w00A, w00A}, w10Av = (v2f){w10A, w10A};
        v2f w01Av = (v2f){w01A, w01A}, w11Av = (v2f){w11A, w11A};
        const float* srcBA = featT + (size_t)((2 * vp + 1) * BB + b) * HWW * CC;
        const float* p00A = srcBA + ((size_t)yc0A * WW + xc0A) * CC;
        int dxA = (xc1A - xc0A) * CC;
        int dyA = (yc1A - yc0A) * (WW * CC);

        // --- view B coords ---
        float rxB = fmaf(prB[1], fy, prB[0] * fx) + prB[2];
        float ryB = fmaf(prB[4], fy, prB[3] * fx) + prB[5];
        float rzB = fmaf(prB[7], fy, prB[6] * fx) + prB[8];
        float XB = rxB * dep + prB[9];
        float YB = ryB * dep + prB[10];
        float ZB = rzB * dep + prB[11];
        if (ZB == 0.f) ZB = 1e-9f;
        float pxB = XB / ZB, pyB = YB / ZB;
        float x0fB = floorf(pxB), y0fB = floorf(pyB);
        float x1fB = x0fB + 1.0f, y1fB = y0fB + 1.0f;
        float wx1B = pxB - x0fB, wx0B = 1.0f - wx1B;
        float wy1B = pyB - y0fB, wy0B = 1.0f - wy1B;
        bool vx0B = (x0fB >= 0.f) && (x0fB <= (float)(WW - 1));
        bool vx1B = (x1fB >= 0.f) && (x1fB <= (float)(WW - 1));
        bool vy0B = (y0fB >= 0.f) && (y0fB <= (float)(HH - 1));
        bool vy1B = (y1fB >= 0.f) && (y1fB <= (float)(HH - 1));
        int xc0B = (int)fminf(fmaxf(x0fB, 0.f), (float)(WW - 1));
        int xc1B = (int)fminf(fmaxf(x1fB, 0.f), (float)(WW - 1));
        int yc0B = (int)fminf(fmaxf(y0fB, 0.f), (float)(HH - 1));
        int yc1B = (int)fminf(fmaxf(y1fB, 0.f), (float)(HH - 1));
        float w00B = (wx0B * wy0B) * ((vx0B && vy0B) ? 1.f : 0.f);
        float w10B = (wx1B * wy0B) * ((vx1B && vy0B) ? 1.f : 0.f);
        float w01B = (wx0B * wy1B) * ((vx0B && vy1B) ? 1.f : 0.f);
        float w11B = (wx1B * wy1B) * ((vx1B && vy1B) ? 1.f : 0.f);
        v2f w00Bv = (v2f){w00B, w00B}, w10Bv = (v2f){w10B, w10B};
        v2f w01Bv = (v2f){w01B, w01B}, w11Bv = (v2f){w11B, w11B};
        const float* srcBB = featT + (size_t)((2 * vp + 2) * BB + b) * HWW * CC;
        const float* p00B = srcBB + ((size_t)yc0B * WW + xc0B) * CC;
        int dxB = (xc1B - xc0B) * CC;
        int dyB = (yc1B - yc0B) * (WW * CC);

        // ---- merged g-loop: both views' loads issued per iteration ----
        float cfA[8], cfB[8];
        float sA = 0.f, sB = 0.f;
#pragma unroll
        for (int g = 0; g < 8; g++) {
            float4 fA00 = *(const float4*)(p00A + 4 * g);
            float4 fA10 = *(const float4*)(p00A + dxA + 4 * g);
            float4 fA01 = *(const float4*)(p00A + dyA + 4 * g);
            float4 fA11 = *(const float4*)(p00A + dxA + dyA + 4 * g);
            float4 fB00 = *(const float4*)(p00B + 4 * g);
            float4 fB10 = *(const float4*)(p00B + dxB + 4 * g);
            float4 fB01 = *(const float4*)(p00B + dyB + 4 * g);
            float4 fB11 = *(const float4*)(p00B + dxB + dyB + 4 * g);

            // shared ref channel pair (identical value/multiply as serial)
            float4 r4 = *(const float4*)&s_ref[pl][g * 4];
            v2f refl = (v2f){r4.x, r4.y};
            v2f refh = (v2f){r4.z, r4.w};

            // ---- view A math (byte-identical chain) ----
            {
                v2f f00l = (v2f){fA00.x, fA00.y}, f00h = (v2f){fA00.z, fA00.w};
                v2f f10l = (v2f){fA10.x, fA10.y}, f10h = (v2f){fA10.z, fA10.w};
                v2f f01l = (v2f){fA01.x, fA01.y}, f01h = (v2f){fA01.z, fA01.w};
                v2f f11l = (v2f){fA11.x, fA11.y}, f11h = (v2f){fA11.z, fA11.w};
                v2f a = f00l * w00Av;
                a = a + f10l * w10Av;
                a = a + f01l * w01Av;
                a = a + f11l * w11Av;
                v2f bq = f00h * w00Av;
                bq = bq + f10h * w10Av;
                bq = bq + f01h * w01Av;
                bq = bq + f11h * w11Av;
                v2f prl = a * refl;
                v2f prh = bq * refh;
                float gs = prl.x;
                gs = gs + prl.y; gs = gs + prh.x; gs = gs + prh.y;
                gs = gs * 0.25f;
                cfA[g] = gs;
                sA = sA + gs;
            }
            // ---- view B math ----
            {
                v2f f00l = (v2f){fB00.x, fB00.y}, f00h = (v2f){fB00.z, fB00.w};
                v2f f10l = (v2f){fB10.x, fB10.y}, f10h = (v2f){fB10.z, fB10.w};
                v2f f01l = (v2f){fB01.x, fB01.y}, f01h = (v2f){fB01.z, fB01.w};
                v2f f11l = (v2f){fB11.x, fB11.y}, f11h = (v2f){fB11.z, fB11.w};
                v2f a = f00l * w00Bv;
                a = a + f10l * w10Bv;
                a = a + f01l * w01Bv;
                a = a + f11l * w11Bv;
                v2f bq = f00h * w00Bv;
                bq = bq + f10h * w10Bv;
                bq = bq + f01h * w01Bv;
                bq = bq + f11h * w11Bv;
                v2f prl = a * refl;
                v2f prh = bq * refh;
                float gs = prl.x;
                gs = gs + prl.y; gs = gs + prh.x; gs = gs + prh.y;
                gs = gs * 0.25f;
                cfB[g] = gs;
                sB = sB + gs;
            }
        }

        // ---- softmax A and B: independent chains, interleaved by scheduler ----
        float mA = sA, mB = sB;
#pragma unroll
        for (int msk = 1; msk < 32; msk <<= 1) {
            mA = fmaxf(mA, __shfl_xor(mA, msk, 64));
            mB = fmaxf(mB, __shfl_xor(mB, msk, 64));
        }
        float eA = expf(sA - mA);
        float eB = expf(sB - mB);
        s_e[0][pl][d] = eA;
        s_e[1][pl][d] = eB;
        float sumA = 0.f, sumB = 0.f;
#pragma unroll
        for (int j = 0; j < 8; j++) {
            float4 qA = *(const float4*)&s_e[0][pl][j * 4];
            float4 qB = *(const float4*)&s_e[1][pl][j * 4];
            sumA = sumA + qA.x; sumA = sumA + qA.y; sumA = sumA + qA.z; sumA = sumA + qA.w;
            sumB = sumB + qB.x; sumB = sumB + qB.y; sumB = sumB + qB.z; sumB = sumB + qB.w;
        }
        float cwA = (eA / sumA) * 0.17677669529663687f;
        float cwB = (eB / sumB) * 0.17677669529663687f;

        // ---- sequential accumulation: A first, then B (original v-order) ----
        cws = cws + cwA;
#pragma unroll
        for (int g = 0; g < 8; g++) {
            float tterm = cwA * cfA[g];
            accs[g] = accs[g] + tterm;
        }
        cws = cws + cwB;
#pragma unroll
        for (int g = 0; g < 8; g++) {
            float tterm = cwB * cfB[g];
            accs[g] = accs[g] + tterm;
        }
    }

    // logit: elementwise /cws then einsum FMA chain over g
    float logit = 0.f;
#pragma unroll
    for (int g = 0; g < 8; g++) {
        float cfn = accs[g] / cws;
        logit = fmaf(s_regw[g], cfn, logit);
    }

    // final softmax over d (same LDS pattern)
    float m2 = logit;
#pragma unroll
    for (int msk = 1; msk < 32; msk <<= 1) m2 = fmaxf(m2, __shfl_xor(m2, msk, 64));
    float e2 = expf(logit - m2);
    s_e[0][pl][d] = e2;
    float s2 = 0.f;
#pragma unroll
    for (int j = 0; j < 8; j++) {
        float4 q = *(const float4*)&s_e[0][pl][j * 4];
        s2 = s2 + q.x; s2 = s2 + q.y; s2 = s2 + q.z; s2 = s2 + q.w;
    }
    float attn = e2 / s2;
    out[(size_t)BB * HWW + (size_t)(b * DD + d) * HWW + hw] = attn;

    // np.argmax: bitwise max (butterfly) + min lane holding it
    float a1 = attn;
#pragma unroll
    for (int msk = 1; msk < 32; msk <<= 1) a1 = fmaxf(a1, __shfl_xor(a1, msk, 64));
    int idx1 = (attn == a1) ? d : 1000;
#pragma unroll
    for (int msk = 1; msk < 32; msk <<= 1) {
        int oi = __shfl_xor(idx1, msk, 64);
        idx1 = (oi < idx1) ? oi : idx1;
    }
    float dep1 = __shfl(dep, base + idx1, 64);
    if (d == 0) out[b * HWW + hw] = dep1;
}

// ---------------------------------------------------------------------------
extern "C" void kernel_launch(void* const* d_in, const int* in_sizes, int n_in,
                              void* d_out, int out_size, void* d_ws, size_t ws_size,
                              hipStream_t stream) {
    const float* features   = (const float*)d_in[0];   // [V,B,C,H,W]
    const float* pm         = (const float*)d_in[1];   // [B,V,2,4,4]
    const float* depth_hypo = (const float*)d_in[2];   // [B,D,H,W]
    const float* reg_w      = (const float*)d_in[3];   // [G]
    float* out = (float*)d_out;                        // depth [B,H,W] ++ attn [B,D,H,W]

    float* wproj = (float*)d_ws;                       // 96 floats
    float* featT = (float*)((char*)d_ws + 4096);       // [VB,H,W,C] = 21 MB

    prep_kernel<<<TRBLOCKS + 1, 256, 0, stream>>>(features, featT, pm, wproj);
    main_kernel<<<BB * HWW / 8, 256, 0, stream>>>(featT, wproj, depth_hypo, reg_w, out);
}

// Round 10
// 147.377 us; speedup vs baseline: 1.1511x; 1.1511x over previous
//
#include <hip/hip_runtime.h>
#include <math.h>

#pragma clang fp contract(off)

#define VV 5
#define BB 2
#define CC 32
#define HH 128
#define WW 128
#define DD 32
#define GG 8
#define HWW (HH*WW)
#define TRBLOCKS (VV*BB*(HWW/64))   // 2560 transpose blocks

typedef float v2f __attribute__((ext_vector_type(2)));

// ---------------------------------------------------------------------------
// Kernel 1 (fused): transpose features [VB,C,H,W] -> [VB,H,W,C]  +  proj setup.
// (unchanged — bit-exact copy; proj math bit-frozen at r9)
// ---------------------------------------------------------------------------
__global__ __launch_bounds__(256) void prep_kernel(const float* __restrict__ fea,
                                                   float* __restrict__ featT,
                                                   const float* __restrict__ pm,
                                                   float* __restrict__ wproj) {
#pragma clang fp contract(off)
    int t = threadIdx.x;
    if (blockIdx.x == TRBLOCKS) {
        int tid = t;
        if (tid >= BB * (VV - 1)) return;
        int b = tid / (VV - 1);
        int v = tid % (VV - 1) + 1;

        float refP[4][4], srcP[4][4];
        for (int which = 0; which < 2; which++) {
            int view = (which == 0) ? 0 : v;
            const float* base = pm + (size_t)(b * VV + view) * 2 * 16;
            const float* ext  = base;
            const float* intr = base + 16;
            float (*M)[4] = (which == 0) ? refP : srcP;
            for (int r = 0; r < 3; r++)
                for (int c = 0; c < 4; c++) {
                    float s = 0.f;
                    for (int k = 0; k < 3; k++)
                        s = fmaf(intr[r * 4 + k], ext[k * 4 + c], s);  // einsum FMA chain
                    M[r][c] = s;
                }
            for (int c = 0; c < 4; c++) M[3][c] = ext[12 + c];
        }

        float A[4][4];
        for (int r = 0; r < 4; r++)
            for (int c = 0; c < 4; c++) A[r][c] = refP[r][c];
        int ipiv[4];
        for (int j = 0; j < 4; j++) {
            int p = j; float amax = fabsf(A[j][j]);
            for (int i = j + 1; i < 4; i++) {
                float tt = fabsf(A[i][j]);
                if (tt > amax) { amax = tt; p = i; }
            }
            ipiv[j] = p;
            if (p != j)
                for (int c = 0; c < 4; c++) { float tt = A[j][c]; A[j][c] = A[p][c]; A[p][c] = tt; }
            float rcp = 1.0f / A[j][j];
            for (int i = j + 1; i < 4; i++) A[i][j] = A[i][j] * rcp;
            for (int i = j + 1; i < 4; i++)
                for (int k = j + 1; k < 4; k++)
                    A[i][k] = fmaf(-A[i][j], A[j][k], A[i][k]);
        }

        float Bm[4][4];
        for (int r = 0; r < 4; r++)
            for (int c = 0; c < 4; c++) Bm[r][c] = (r == c) ? 1.f : 0.f;
        for (int j = 0; j < 4; j++) {
            int p = ipiv[j];
            if (p != j)
                for (int c = 0; c < 4; c++) { float tt = Bm[j][c]; Bm[j][c] = Bm[p][c]; Bm[p][c] = tt; }
        }
        float invd[4];
        for (int k = 0; k < 4; k++) invd[k] = 1.0f / A[k][k];
        for (int c = 0; c < 4; c++) {
            for (int k = 0; k < 4; k++)
                for (int i = k + 1; i < 4; i++)
                    Bm[i][c] = fmaf(-A[i][k], Bm[k][c], Bm[i][c]);
            for (int k = 3; k >= 0; k--) {
                Bm[k][c] = Bm[k][c] * invd[k];
                for (int i = 0; i < k; i++)
                    Bm[i][c] = fmaf(-A[i][k], Bm[k][c], Bm[i][c]);
            }
        }

        float P[3][4];
        for (int r = 0; r < 3; r++)
            for (int c = 0; c < 4; c++) {
                float s = 0.f;
                for (int k = 0; k < 4; k++)
                    s = fmaf(srcP[r][k], Bm[k][c], s);
                P[r][c] = s;
            }
        float* o = wproj + (b * (VV - 1) + (v - 1)) * 12;
        for (int r = 0; r < 3; r++)
            for (int c = 0; c < 3; c++) o[r * 3 + c] = P[r][c];
        for (int r = 0; r < 3; r++) o[9 + r] = P[r][3];
        return;
    }

    __shared__ float tile[64][36];
    int vb = blockIdx.x >> 8;
    int base = (blockIdx.x & 255) * 64;
#pragma unroll
    for (int k = 0; k < 2; k++) {
        int c = (t >> 4) + 16 * k;
        int p = t & 15;
        float4 v = *(const float4*)&fea[((size_t)vb * CC + c) * HWW + base + 4 * p];
        int cs = c ^ ((p & 7) << 2);
        tile[4 * p + 0][cs] = v.x;
        tile[4 * p + 1][cs] = v.y;
        tile[4 * p + 2][cs] = v.z;
        tile[4 * p + 3][cs] = v.w;
    }
    __syncthreads();
#pragma unroll
    for (int m = 0; m < 2; m++) {
        int pl = (t >> 3) + 32 * m;
        int q = t & 7;
        int sw = ((pl >> 2) & 7) << 2;
        float4 v = *(const float4*)&tile[pl][(4 * q) ^ sw];
        *(float4*)&featT[((size_t)vb * HWW + base + pl) * CC + 4 * q] = v;
    }
}

// ---------------------------------------------------------------------------
// Kernel 2: VIEW-PARALLEL, 256-thread blocks = 2 px x 4 views x 32 d,
// PHASE-2-ONCE on wave 0. t = vi*64 + px*32 + d (wave = one view).
// Ledger (stall-time = dur x (1-VALUBusy)): R1's 16K small 4-wave blocks is
// the ONLY structure that cut stall (29 us vs 40-43 everywhere else); its loss
// was x4-redundant phase-2 (+29 us VALU) and write amp. R6's phase-2-once
// used 8-wave blocks and stall reverted. This round: R1 geometry + phase-2
// once on wave 0 (64 lanes = 2px x 32d, dep register carries over exactly).
// Work = serial kernel's; blocks = 16384 small independent staggered blocks;
// VGPR ~32-40 -> 8 blocks/CU. R7 XCD swizzle kept (16384 % 8 == 0).
// Accepted cost: attn writes 8B/32B sector (~17 MB, +1.5 us at 3% BW).
// Bit-exact: phase-1 chain = R1's verified body; combine = R4/R6 verified
// v-order; s_e rows private per (vi,px); phase-2 reuses rows 0-1 post-barrier.
// (R9 bench was an infra failure — container died twice; identical resubmit.)
// ---------------------------------------------------------------------------
__global__ __launch_bounds__(256) void main_kernel(const float* __restrict__ featT,
                                                   const float* __restrict__ wproj,
                                                   const float* __restrict__ depth_hypo,
                                                   const float* __restrict__ reg_w,
                                                   float* __restrict__ out) {
#pragma clang fp contract(off)
    __shared__ float s_ref[2][32];       // ref features per pixel
    __shared__ float s_e[8][32];         // softmax round-trip, row = vi*2+px
    __shared__ float s_proj[4][12];
    __shared__ float s_regw[8];
    __shared__ float s_cw[2][4][32];     // per-view softmax weight  [px][v][d]
    __shared__ float s_cf[2][4][8][32];  // per-view correlation     [px][v][g][d]

    int t = threadIdx.x;
    int d   = t & 31;            // depth hypothesis
    int px  = (t >> 5) & 1;      // pixel within block
    int vi  = t >> 6;            // view - 1  (wave index)
    int row = t >> 5;            // vi*2 + px: unique 32-lane softmax group id
    int base = t & 32;           // lane base of this 32-lane group inside wave

    // XCD-aware bijective swizzle (R7; nwg = 16384, 16384/8 = 2048)
    int bid = blockIdx.x;
    int swz = (bid & 7) * (16384 >> 3) + (bid >> 3);

    int pixbase = swz * 2;
    int b = pixbase / HWW;
    int hwb = pixbase - b * HWW;

    if (t < 64) s_ref[t >> 5][t & 31] = featT[((size_t)(b * HWW + hwb + (t >> 5))) * CC + (t & 31)];
    if (t < 48) s_proj[t / 12][t % 12] = wproj[b * (VV - 1) * 12 + t];
    if (t < 8) s_regw[t] = reg_w[t];
    __syncthreads();

    int hw = hwb + px;
    int y = hw >> 7, x = hw & (WW - 1);
    float fx = (float)x, fy = (float)y;
    float dep = depth_hypo[(size_t)(b * DD + d) * HWW + hw];

    // ---- phase 1: this thread's single view (bit-identical chain) ----
    const float* pr = s_proj[vi];
    float rx = fmaf(pr[1], fy, pr[0] * fx) + pr[2];
    float ry = fmaf(pr[4], fy, pr[3] * fx) + pr[5];
    float rz = fmaf(pr[7], fy, pr[6] * fx) + pr[8];
    float X = rx * dep + pr[9];
    float Y = ry * dep + pr[10];
    float Z = rz * dep + pr[11];
    if (Z == 0.f) Z = 1e-9f;
    float px_ = X / Z, py_ = Y / Z;

    float x0f = floorf(px_), y0f = floorf(py_);
    float x1f = x0f + 1.0f, y1f = y0f + 1.0f;
    float wx1 = px_ - x0f, wx0 = 1.0f - wx1;
    float wy1 = py_ - y0f, wy0 = 1.0f - wy1;
    bool vx0 = (x0f >= 0.f) && (x0f <= (float)(WW - 1));
    bool vx1 = (x1f >= 0.f) && (x1f <= (float)(WW - 1));
    bool vy0 = (y0f >= 0.f) && (y0f <= (float)(HH - 1));
    bool vy1 = (y1f >= 0.f) && (y1f <= (float)(HH - 1));

    int xc0 = (int)fminf(fmaxf(x0f, 0.f), (float)(WW - 1));
    int xc1 = (int)fminf(fmaxf(x1f, 0.f), (float)(WW - 1));
    int yc0 = (int)fminf(fmaxf(y0f, 0.f), (float)(HH - 1));
    int yc1 = (int)fminf(fmaxf(y1f, 0.f), (float)(HH - 1));

    float w00 = (wx0 * wy0) * ((vx0 && vy0) ? 1.f : 0.f);
    float w10 = (wx1 * wy0) * ((vx1 && vy0) ? 1.f : 0.f);
    float w01 = (wx0 * wy1) * ((vx0 && vy1) ? 1.f : 0.f);
    float w11 = (wx1 * wy1) * ((vx1 && vy1) ? 1.f : 0.f);

    v2f w00v = (v2f){w00, w00};
    v2f w10v = (v2f){w10, w10};
    v2f w01v = (v2f){w01, w01};
    v2f w11v = (v2f){w11, w11};

    // one base pointer + int deltas (identical addresses as 4 pointers)
    const float* srcB = featT + (size_t)((vi + 1) * BB + b) * HWW * CC;
    const float* p00 = srcB + ((size_t)yc0 * WW + xc0) * CC;
    int dx = (xc1 - xc0) * CC;            // 0 or 32 floats
    int dy = (yc1 - yc0) * (WW * CC);     // 0 or 4096 floats

    float cf[8];
    float s = 0.f;
#pragma unroll
    for (int g = 0; g < 8; g++) {
        float4 f00 = *(const float4*)(p00 + 4 * g);
        float4 f10 = *(const float4*)(p00 + dx + 4 * g);
        float4 f01 = *(const float4*)(p00 + dy + 4 * g);
        float4 f11 = *(const float4*)(p00 + dx + dy + 4 * g);
        v2f f00l = (v2f){f00.x, f00.y}, f00h = (v2f){f00.z, f00.w};
        v2f f10l = (v2f){f10.x, f10.y}, f10h = (v2f){f10.z, f10.w};
        v2f f01l = (v2f){f01.x, f01.y}, f01h = (v2f){f01.z, f01.w};
        v2f f11l = (v2f){f11.x, f11.y}, f11h = (v2f){f11.z, f11.w};

        // warped = ((t00*w00 + t10*w10) + t01*w01) + t11*w11, per channel;
        // packed pairs, separate mul/add (contract off) — bit-exact per lane
        v2f a = f00l * w00v;
        a = a + f10l * w10v;
        a = a + f01l * w01v;
        a = a + f11l * w11v;
        v2f bq = f00h * w00v;
        bq = bq + f10h * w10v;
        bq = bq + f01h * w01v;
        bq = bq + f11h * w11v;

        // ref channel pair from LDS (broadcast, conflict-free)
        float4 r4 = *(const float4*)&s_ref[px][g * 4];
        v2f refl = (v2f){r4.x, r4.y};
        v2f refh = (v2f){r4.z, r4.w};

        v2f prl = a * refl;
        v2f prh = bq * refh;

        // gs = ((pr0 + pr1) + pr2) + pr3  (exact original order)
        float gs = prl.x;
        gs = gs + prl.y; gs = gs + prh.x; gs = gs + prh.y;
        gs = gs * 0.25f;
        cf[g] = gs;
        s = s + gs;
    }

    // per-view softmax over d: max butterfly (order-free), denominator via LDS
    // round-trip + SAME sequential d-order adds (bit-identical).
    float m = s;
#pragma unroll
    for (int msk = 1; msk < 32; msk <<= 1) m = fmaxf(m, __shfl_xor(m, msk, 64));
    float e = expf(s - m);
    s_e[row][d] = e;
    float sum = 0.f;
#pragma unroll
    for (int j = 0; j < 8; j++) {
        float4 q = *(const float4*)&s_e[row][j * 4];
        sum = sum + q.x; sum = sum + q.y; sum = sum + q.z; sum = sum + q.w;
    }
    float cw = (e / sum) * 0.17677669529663687f;

    // publish this view's results (d-consecutive -> conflict-free)
    s_cw[px][vi][d] = cw;
#pragma unroll
    for (int g = 0; g < 8; g++) s_cf[px][vi][g][d] = cf[g];
    __syncthreads();

    if (t >= 64) return;   // waves 1-3 done (past the barrier); wave 0 continues

    // ---- phase 2 (wave 0 only: 64 lanes = 2 px x 32 d; px = t>>5 as above,
    //      dep register carries over since wave 0's phase-1 had vi=0, same px,d)
    // combine views in ORIGINAL v=1..4 order: same add/mul sequence as serial
    float cws = 1e-8f;
    float accs[8];
#pragma unroll
    for (int g = 0; g < 8; g++) accs[g] = 0.f;
#pragma unroll
    for (int v = 0; v < 4; v++) {
        float cwv = s_cw[px][v][d];
        cws = cws + cwv;
#pragma unroll
        for (int g = 0; g < 8; g++) {
            float tterm = cwv * s_cf[px][v][g][d];
            accs[g] = accs[g] + tterm;
        }
    }

    // logit: elementwise /cws then einsum FMA chain over g
    float logit = 0.f;
#pragma unroll
    for (int g = 0; g < 8; g++) {
        float cfn = accs[g] / cws;
        logit = fmaf(s_regw[g], cfn, logit);
    }

    // final softmax over d (same LDS pattern; rows 0-1 reused post-barrier)
    float m2 = logit;
#pragma unroll
    for (int msk = 1; msk < 32; msk <<= 1) m2 = fmaxf(m2, __shfl_xor(m2, msk, 64));
    float e2 = expf(logit - m2);
    s_e[px][d] = e2;
    float s2 = 0.f;
#pragma unroll
    for (int j = 0; j < 8; j++) {
        float4 q = *(const float4*)&s_e[px][j * 4];
        s2 = s2 + q.x; s2 = s2 + q.y; s2 = s2 + q.z; s2 = s2 + q.w;
    }
    float attn = e2 / s2;
    out[(size_t)BB * HWW + (size_t)(b * DD + d) * HWW + hw] = attn;

    // np.argmax: bitwise max (butterfly) + min lane holding it
    float a1 = attn;
#pragma unroll
    for (int msk = 1; msk < 32; msk <<= 1) a1 = fmaxf(a1, __shfl_xor(a1, msk, 64));
    int idx1 = (attn == a1) ? d : 1000;
#pragma unroll
    for (int msk = 1; msk < 32; msk <<= 1) {
        int oi = __shfl_xor(idx1, msk, 64);
        idx1 = (oi < idx1) ? oi : idx1;
    }
    float dep1 = __shfl(dep, base + idx1, 64);
    if (d == 0) out[b * HWW + hw] = dep1;
}

// ---------------------------------------------------------------------------
extern "C" void kernel_launch(void* const* d_in, const int* in_sizes, int n_in,
                              void* d_out, int out_size, void* d_ws, size_t ws_size,
                              hipStream_t stream) {
    const float* features   = (const float*)d_in[0];   // [V,B,C,H,W]
    const float* pm         = (const float*)d_in[1];   // [B,V,2,4,4]
    const float* depth_hypo = (const float*)d_in[2];   // [B,D,H,W]
    const float* reg_w      = (const float*)d_in[3];   // [G]
    float* out = (float*)d_out;                        // depth [B,H,W] ++ attn [B,D,H,W]

    float* wproj = (float*)d_ws;                       // 96 floats
    float* featT = (float*)((char*)d_ws + 4096);       // [VB,H,W,C] = 21 MB

    prep_kernel<<<TRBLOCKS + 1, 256, 0, stream>>>(features, featT, pm, wproj);
    main_kernel<<<BB * HWW / 2, 256, 0, stream>>>(featT, wproj, depth_hypo, reg_w, out);
}